// Round 7
// baseline (2206.655 us; speedup 1.0000x reference)
//
#include <hip/hip_runtime.h>
#include <math.h>

#define NPOINTS 16384
#define KNN     32
#define NBASIS  27

// ===================== helpers =====================

__device__ __forceinline__ unsigned fkey(float f) {
  // monotone order-preserving map fp32 -> uint32
  unsigned u = __float_as_uint(f);
  return (u & 0x80000000u) ? ~u : (u | 0x80000000u);
}

// Ballot-aggregated LDS histogram add: one atomic per DISTINCT bin per wave op.
// The d2 keys are exponent-concentrated (~10 live bins), which made plain
// per-lane atomicAdd serialize ~64-deep (1.5e8 bank-conflict cycles, r6 PMC).
__device__ __forceinline__ void hist_add(unsigned* hist, bool in, unsigned bin, int lane) {
  unsigned long long active = __ballot(in);
  while (active) {
    int leader = __ffsll((long long)active) - 1;
    unsigned lbin = (unsigned)__shfl((int)bin, leader);
    unsigned long long same = __ballot(in && (bin == lbin));
    if (in && lane == leader) atomicAdd(&hist[lbin], (unsigned)__popcll(same));
    active &= ~same;
  }
}

// ===================== faithful ssyevd(3x3) port (double arith, fp32 eps) ============

__device__ __forceinline__ void slartg_dev(double f, double g, double* c, double* s, double* r) {
#pragma clang fp contract(off)
  // LAPACK >= 3.10 convention (c >= 0)
  if (g == 0.0) { *c = 1.0; *s = 0.0; *r = f; }
  else if (f == 0.0) { *c = 0.0; *s = (g >= 0.0 ? 1.0 : -1.0); *r = fabs(g); }
  else {
    double d = sqrt(f * f + g * g);
    *c = fabs(f) / d;
    *r = (f >= 0.0) ? d : -d;
    *s = g / (*r);
  }
}

__device__ __forceinline__ void slaev2_dev(double a, double b, double c,
                                           double* rt1, double* rt2, double* cs1, double* sn1) {
#pragma clang fp contract(off)
  double sm = a + c, df = a - c, adf = fabs(df), tb = b + b, ab = fabs(tb);
  double acmx, acmn;
  if (fabs(a) > fabs(c)) { acmx = a; acmn = c; } else { acmx = c; acmn = a; }
  double rt;
  if (adf > ab)      rt = adf * sqrt(1.0 + (ab / adf) * (ab / adf));
  else if (adf < ab) rt = ab * sqrt(1.0 + (adf / ab) * (adf / ab));
  else               rt = ab * sqrt(2.0);
  int sgn1;
  if (sm < 0.0) { *rt1 = 0.5 * (sm - rt); sgn1 = -1; *rt2 = (acmx / *rt1) * acmn - (b / *rt1) * b; }
  else if (sm > 0.0) { *rt1 = 0.5 * (sm + rt); sgn1 = 1; *rt2 = (acmx / *rt1) * acmn - (b / *rt1) * b; }
  else { *rt1 = 0.5 * rt; *rt2 = -0.5 * rt; sgn1 = 1; }
  int sgn2; double cs;
  if (df >= 0.0) { cs = df + rt; sgn2 = 1; } else { cs = df - rt; sgn2 = -1; }
  double acs = fabs(cs);
  if (acs > ab) { double ct = -tb / cs; double sn = 1.0 / sqrt(1.0 + ct * ct); *sn1 = sn; *cs1 = ct * sn; }
  else {
    if (ab == 0.0) { *cs1 = 1.0; *sn1 = 0.0; }
    else { double tn = -cs / tb; double c1 = 1.0 / sqrt(1.0 + tn * tn); *cs1 = c1; *sn1 = tn * c1; }
  }
  if (sgn1 == sgn2) { double tn = *cs1; *cs1 = -(*sn1); *sn1 = tn; }
}

// Input: lower triangle of symmetric 3x3 (fp32 cov). Output: V columns in DESCENDING
// eigenvalue order (LAPACK ascending, reversed) = np/jnp eigh + [:, :, ::-1].
__device__ void eigh3(float A00, float A10, float A20, float A11, float A21, float A22,
                      float V[3][3]) {
#pragma clang fp contract(off)
  const double EPS    = 5.9604644775390625e-08;   // fp32 slamch('E')
  const double EPS2   = EPS * EPS;
  const double SAFMIN = 1.1754943508222875e-38;   // fp32 slamch('S')
  double d[3], e[2];
  double tau = 0.0, v2 = 0.0;
  // ---- ssytd2 (uplo='L'), single Householder on [A10; A20]
  {
    double alpha = (double)A10, x = (double)A20;
    double a11 = (double)A11, a21 = (double)A21, a22 = (double)A22;
    double beta;
    if (x == 0.0) { tau = 0.0; v2 = 0.0; beta = alpha; }
    else {
      double nrm = sqrt(alpha * alpha + x * x);          // slapy2
      beta = (alpha >= 0.0) ? -nrm : nrm;                // -sign(nrm, alpha)
      tau = (beta - alpha) / beta;
      v2 = x / (alpha - beta);
    }
    if (tau != 0.0) {
      double w0 = tau * (a11 + a21 * v2);
      double w1 = tau * (a21 + a22 * v2);
      double cc = 0.5 * tau * (w0 + w1 * v2);
      w0 -= cc; w1 -= cc * v2;
      a11 -= 2.0 * w0;
      a21 -= (v2 * w0 + w1);
      a22 -= 2.0 * v2 * w1;
    }
    d[0] = (double)A00; d[1] = a11; d[2] = a22;
    e[0] = beta; e[1] = a21;
  }
  double Z[3][3] = { {1.0, 0.0, 0.0}, {0.0, 1.0, 0.0}, {0.0, 0.0, 1.0} };
  // ---- ssteqr('I', n=3)
  {
    int l1 = 1, jtot = 0;
    const int nmaxit = 90;
    double wc[2], wsn[2];
    while (l1 <= 3) {
      if (l1 > 1) e[l1 - 2] = 0.0;
      int m = 3;
      for (int mm = l1; mm <= 2; ++mm) {
        double tst = fabs(e[mm - 1]);
        if (tst == 0.0) { m = mm; break; }
        if (tst <= (sqrt(fabs(d[mm - 1])) * sqrt(fabs(d[mm]))) * EPS) { e[mm - 1] = 0.0; m = mm; break; }
      }
      int l = l1, lsv = l, lend = m, lendsv = lend;
      l1 = m + 1;
      if (lend == l) continue;
      double anorm = 0.0;
      for (int i = l; i <= lend; ++i)     anorm = fmax(anorm, fabs(d[i - 1]));
      for (int i = l; i <= lend - 1; ++i) anorm = fmax(anorm, fabs(e[i - 1]));
      if (anorm == 0.0) continue;
      if (fabs(d[lend - 1]) < fabs(d[l - 1])) { lend = lsv; l = lendsv; }
      if (lend > l) {
        // ===== QL =====
        bool done = false;
        while (!done) {
          int mq = lend;
          for (int mm = l; mm <= lend - 1; ++mm) {
            double tst = e[mm - 1] * e[mm - 1];
            if (tst <= (EPS2 * fabs(d[mm - 1])) * fabs(d[mm]) + SAFMIN) { mq = mm; break; }
          }
          if (mq < lend) e[mq - 1] = 0.0;
          double p = d[l - 1];
          if (mq == l) { d[l - 1] = p; ++l; if (l > lend) done = true; continue; }
          if (mq == l + 1) {
            double rt1, rt2, cc, ssn;
            slaev2_dev(d[l - 1], e[l - 1], d[l], &rt1, &rt2, &cc, &ssn);
            for (int i = 0; i < 3; ++i) {
              double t = Z[i][l];
              Z[i][l]     = cc * t - ssn * Z[i][l - 1];
              Z[i][l - 1] = ssn * t + cc * Z[i][l - 1];
            }
            d[l - 1] = rt1; d[l] = rt2; e[l - 1] = 0.0;
            l += 2; if (l > lend) done = true; continue;
          }
          if (jtot >= nmaxit) break;
          ++jtot;
          double g = (d[l] - p) / (2.0 * e[l - 1]);
          double r = sqrt(g * g + 1.0);
          g = d[mq - 1] - p + e[l - 1] / (g + ((g >= 0.0) ? r : -r));
          double ssn = 1.0, cc = 1.0;
          p = 0.0;
          for (int i = mq - 1; i >= l; --i) {
            double f = ssn * e[i - 1], b = cc * e[i - 1];
            slartg_dev(g, f, &cc, &ssn, &r);
            if (i != mq - 1) e[i] = r;
            g = d[i] - p;
            r = (d[i - 1] - g) * ssn + 2.0 * cc * b;
            p = ssn * r;
            d[i] = g + p;
            g = cc * r - b;
            wc[i - 1] = cc; wsn[i - 1] = -ssn;
          }
          for (int j = mq - 1; j >= l; --j) {
            double cj = wc[j - 1], sj = wsn[j - 1];
            for (int i = 0; i < 3; ++i) {
              double t = Z[i][j];
              Z[i][j]     = cj * t - sj * Z[i][j - 1];
              Z[i][j - 1] = sj * t + cj * Z[i][j - 1];
            }
          }
          d[l - 1] -= p; e[l - 1] = g;
        }
      } else {
        // ===== QR =====
        bool done = false;
        while (!done) {
          int mq = lend;
          for (int mm = l; mm >= lend + 1; --mm) {
            double tst = e[mm - 2] * e[mm - 2];
            if (tst <= (EPS2 * fabs(d[mm - 1])) * fabs(d[mm - 2]) + SAFMIN) { mq = mm; break; }
          }
          if (mq > lend) e[mq - 2] = 0.0;
          double p = d[l - 1];
          if (mq == l) { d[l - 1] = p; --l; if (l < lend) done = true; continue; }
          if (mq == l - 1) {
            double rt1, rt2, cc, ssn;
            slaev2_dev(d[l - 2], e[l - 2], d[l - 1], &rt1, &rt2, &cc, &ssn);
            for (int i = 0; i < 3; ++i) {
              double t = Z[i][l - 1];
              Z[i][l - 1] = cc * t - ssn * Z[i][l - 2];
              Z[i][l - 2] = ssn * t + cc * Z[i][l - 2];
            }
            d[l - 2] = rt1; d[l - 1] = rt2; e[l - 2] = 0.0;
            l -= 2; if (l < lend) done = true; continue;
          }
          if (jtot >= nmaxit) break;
          ++jtot;
          double g = (d[l - 2] - p) / (2.0 * e[l - 2]);
          double r = sqrt(g * g + 1.0);
          g = d[mq - 1] - p + e[l - 2] / (g + ((g >= 0.0) ? r : -r));
          double ssn = 1.0, cc = 1.0;
          p = 0.0;
          for (int i = mq; i <= l - 1; ++i) {
            double f = ssn * e[i - 1], b = cc * e[i - 1];
            slartg_dev(g, f, &cc, &ssn, &r);
            if (i != mq) e[i - 2] = r;
            g = d[i - 1] - p;
            r = (d[i] - g) * ssn + 2.0 * cc * b;
            p = ssn * r;
            d[i - 1] = g + p;
            g = cc * r - b;
            wc[i - 1] = cc; wsn[i - 1] = ssn;
          }
          for (int j = mq; j <= l - 1; ++j) {
            double cj = wc[j - 1], sj = wsn[j - 1];
            for (int i = 0; i < 3; ++i) {
              double t = Z[i][j];
              Z[i][j]     = cj * t - sj * Z[i][j - 1];
              Z[i][j - 1] = sj * t + cj * Z[i][j - 1];
            }
          }
          d[l - 1] -= p; e[l - 2] = g;
        }
      }
    }
    // ---- ascending selection sort with column swaps (as in ssteqr)
    for (int ii = 2; ii <= 3; ++ii) {
      int i0 = ii - 1, k = i0;
      double p = d[i0 - 1];
      for (int j = ii; j <= 3; ++j) if (d[j - 1] < p) { k = j; p = d[j - 1]; }
      if (k != i0) {
        d[k - 1] = d[i0 - 1]; d[i0 - 1] = p;
        for (int rr = 0; rr < 3; ++rr) { double t = Z[rr][i0 - 1]; Z[rr][i0 - 1] = Z[rr][k - 1]; Z[rr][k - 1] = t; }
      }
    }
  }
  // ---- sormtr: Z := H1 * Z
  if (tau != 0.0) {
    for (int j = 0; j < 3; ++j) {
      double w = Z[1][j] + v2 * Z[2][j];
      Z[1][j] -= tau * w;
      Z[2][j] -= tau * v2 * w;
    }
  }
  for (int i = 0; i < 3; ++i)
    for (int j = 0; j < 3; ++j)
      V[i][j] = (float)Z[i][2 - j];
}

// ===================== kernel 1: exact KNN (top-32 of fp32 d2, chain A) =====================
#define ROWS  16
#define TILE  1024
#define NTILES (NPOINTS / TILE)

// Chain A: OpenBLAS sgemm K=3 microkernel order: c=x*x'; c=fma(y,y',c); c=fma(z,z',c)
__device__ __forceinline__ float mdot_f(float rx, float ry, float rz,
                                        float bx, float by, float bz) {
#pragma clang fp contract(off)
  return __builtin_fmaf(rz, bz, __builtin_fmaf(ry, by, rx * bx));
}

__global__ __launch_bounds__(256) void knn_kernel(const float* __restrict__ pos,
                                                  unsigned* __restrict__ idx_out) {
#pragma clang fp contract(off)
  __shared__ float sx[TILE], sy[TILE], sz[TILE], ssq[TILE];
  __shared__ float rx_[ROWS], ry_[ROWS], rz_[ROWS], rsq_[ROWS];
  __shared__ unsigned hist[ROWS][256];
  __shared__ unsigned b0_[ROWS], cb0_[ROWS], p16_[ROWS];
  __shared__ unsigned selbuf[ROWS][48];
  __shared__ unsigned selkey[ROWS][48];
  __shared__ unsigned eqk[ROWS][64], eqi[ROWS][64];
  __shared__ unsigned selcnt_[ROWS], eqcnt_[ROWS];

  const int tid  = threadIdx.x;
  const int lane = tid & 63;
  const int wave = tid >> 6;
  const int R0   = blockIdx.x * ROWS;

  if (tid < ROWS) {
    float x = pos[(R0 + tid) * 3 + 0];
    float y = pos[(R0 + tid) * 3 + 1];
    float z = pos[(R0 + tid) * 3 + 2];
    rx_[tid] = x; ry_[tid] = y; rz_[tid] = z;
    rsq_[tid] = (x * x + y * y) + z * z;
    selcnt_[tid] = 0u; eqcnt_[tid] = 0u;
  }
  for (int i = tid; i < ROWS * 256; i += 256) (&hist[0][0])[i] = 0u;
  __syncthreads();

  // ---------- pass 1: histogram of key bits [31:24] (ballot-aggregated) ----------
  for (int t = 0; t < NTILES; ++t) {
    for (int j = tid; j < TILE; j += 256) {
      int col = t * TILE + j;
      float x = pos[col * 3 + 0], y = pos[col * 3 + 1], z = pos[col * 3 + 2];
      sx[j] = x; sy[j] = y; sz[j] = z;
      ssq[j] = (x * x + y * y) + z * z;
    }
    __syncthreads();
    for (int rr = 0; rr < ROWS / 4; ++rr) {
      int r = wave * (ROWS / 4) + rr;
      float rx = rx_[r], ry = ry_[r], rz = rz_[r], rq = rsq_[r];
      for (int ch = 0; ch < TILE / 64; ++ch) {
        int j = ch * 64 + lane;
        float mdot = mdot_f(rx, ry, rz, sx[j], sy[j], sz[j]);
        float d2 = (rq + ssq[j]) - 2.0f * mdot;
        unsigned key = fkey(d2);
        hist_add(&hist[r][0], true, key >> 24, lane);
      }
    }
    __syncthreads();
  }
  if (tid < ROWS) {
    unsigned cum = 0, b0 = 255, cb = 0;
    for (int b = 0; b < 256; ++b) {
      unsigned h = hist[tid][b];
      if (cum + h >= (unsigned)KNN) { b0 = (unsigned)b; cb = cum; break; }
      cum += h;
    }
    b0_[tid] = b0; cb0_[tid] = cb;
  }
  __syncthreads();
  for (int i = tid; i < ROWS * 256; i += 256) (&hist[0][0])[i] = 0u;
  __syncthreads();

  // ---------- pass 2: histogram of key bits [23:16] within top byte (ballot-aggregated) ----
  for (int t = 0; t < NTILES; ++t) {
    for (int j = tid; j < TILE; j += 256) {
      int col = t * TILE + j;
      float x = pos[col * 3 + 0], y = pos[col * 3 + 1], z = pos[col * 3 + 2];
      sx[j] = x; sy[j] = y; sz[j] = z;
      ssq[j] = (x * x + y * y) + z * z;
    }
    __syncthreads();
    for (int rr = 0; rr < ROWS / 4; ++rr) {
      int r = wave * (ROWS / 4) + rr;
      float rx = rx_[r], ry = ry_[r], rz = rz_[r], rq = rsq_[r];
      unsigned ub0 = b0_[r];
      for (int ch = 0; ch < TILE / 64; ++ch) {
        int j = ch * 64 + lane;
        float mdot = mdot_f(rx, ry, rz, sx[j], sy[j], sz[j]);
        float d2 = (rq + ssq[j]) - 2.0f * mdot;
        unsigned key = fkey(d2);
        hist_add(&hist[r][0], (key >> 24) == ub0, (key >> 16) & 255u, lane);
      }
    }
    __syncthreads();
  }
  if (tid < ROWS) {
    unsigned cum = cb0_[tid];
    unsigned p16 = (b0_[tid] << 8) | 255u;
    for (int b = 0; b < 256; ++b) {
      unsigned h = hist[tid][b];
      if (cum + h >= (unsigned)KNN) { p16 = (b0_[tid] << 8) | (unsigned)b; break; }
      cum += h;
    }
    p16_[tid] = p16;
  }
  __syncthreads();

  // ---------- pass 3: deterministic compaction of LT / EQ candidates ----------
  for (int t = 0; t < NTILES; ++t) {
    for (int j = tid; j < TILE; j += 256) {
      int col = t * TILE + j;
      float x = pos[col * 3 + 0], y = pos[col * 3 + 1], z = pos[col * 3 + 2];
      sx[j] = x; sy[j] = y; sz[j] = z;
      ssq[j] = (x * x + y * y) + z * z;
    }
    __syncthreads();
    for (int rr = 0; rr < ROWS / 4; ++rr) {
      int r = wave * (ROWS / 4) + rr;
      float rx = rx_[r], ry = ry_[r], rz = rz_[r], rq = rsq_[r];
      unsigned P = p16_[r];
      unsigned base = selcnt_[r];
      unsigned eb = eqcnt_[r];
      for (int ch = 0; ch < TILE / 64; ++ch) {
        int j = ch * 64 + lane;
        unsigned jg = (unsigned)(t * TILE + j);
        float mdot = mdot_f(rx, ry, rz, sx[j], sy[j], sz[j]);
        float d2 = (rq + ssq[j]) - 2.0f * mdot;
        unsigned key = fkey(d2);
        unsigned k16 = key >> 16;
        bool lt = (k16 < P), eq = (k16 == P);
        unsigned long long mlt = __ballot(lt);
        if (lt) {
          unsigned slot = base + (unsigned)__popcll(mlt & ((1ULL << lane) - 1ULL));
          if (slot < 48u) { selbuf[r][slot] = jg; selkey[r][slot] = key; }
        }
        base += (unsigned)__popcll(mlt);
        unsigned long long meq = __ballot(eq);
        if (eq) {
          unsigned slot = eb + (unsigned)__popcll(meq & ((1ULL << lane) - 1ULL));
          if (slot < 64u) { eqk[r][slot] = key; eqi[r][slot] = jg; }
        }
        eb += (unsigned)__popcll(meq);
      }
      if (lane == 0) { selcnt_[r] = base; eqcnt_[r] = eb; }
    }
    __syncthreads();
  }

  // ---------- finalize: LT all + EQ tail by (key asc, idx DESC); emit sorted (key, idx) ----
  // TIE-BREAK (verified r6): among bit-equal fp32 keys prefer the HIGHER index.
  if (tid < ROWS) {
    int r = tid;
    unsigned nlt = selcnt_[r]; if (nlt > (unsigned)KNN) nlt = KNN;
    unsigned neq = eqcnt_[r];  if (neq > 64u) neq = 64u;
    int need = KNN - (int)nlt;
    unsigned kk[KNN], ii[KNN];
    unsigned w = 0;
    for (; w < nlt; ++w) { kk[w] = selkey[r][w]; ii[w] = selbuf[r][w]; }
    unsigned long long used = 0ULL;
    for (int s = 0; s < need; ++s) {
      unsigned bkey = 0xFFFFFFFFu, bidx = 0u; int bj = -1;
      for (int jq = 0; jq < (int)neq; ++jq) {
        if ((used >> jq) & 1ULL) continue;
        unsigned kq = eqk[r][jq], iq = eqi[r][jq];
        if (bj < 0 || kq < bkey || (kq == bkey && iq > bidx)) { bkey = kq; bidx = iq; bj = jq; }
      }
      if (bj < 0) { kk[w] = 0xFFFFFFFFu; ii[w] = (unsigned)(R0 + r); ++w; continue; }
      used |= (1ULL << bj);
      kk[w] = bkey; ii[w] = bidx; ++w;
    }
    // emission order: (key asc, idx asc) — matches top_k output order
    for (int a = 1; a < KNN; ++a) {
      unsigned ka = kk[a], ia = ii[a];
      int bpos = a - 1;
      while (bpos >= 0 && (kk[bpos] > ka || (kk[bpos] == ka && ii[bpos] > ia))) {
        kk[bpos + 1] = kk[bpos]; ii[bpos + 1] = ii[bpos]; --bpos;
      }
      kk[bpos + 1] = ka; ii[bpos + 1] = ia;
    }
    unsigned ob = (unsigned)(R0 + r) * KNN;
    for (int a = 0; a < KNN; ++a) idx_out[ob + a] = ii[a];
  }
}

// ===================== kernel 2: mean + cov + eigh per point (fp32) =====================
__global__ __launch_bounds__(256) void pca_kernel(const float* __restrict__ pos,
                                                  const unsigned* __restrict__ idx,
                                                  float* __restrict__ center,
                                                  float* __restrict__ Vmat) {
#pragma clang fp contract(off)
  int n = blockIdx.x * 256 + threadIdx.x;
  if (n >= NPOINTS) return;
  float sx = 0.f, sy = 0.f, sz = 0.f;
  for (int k = 0; k < KNN; ++k) {
    unsigned j = idx[n * KNN + k];
    sx += pos[j * 3 + 0];
    sy += pos[j * 3 + 1];
    sz += pos[j * 3 + 2];
  }
  float cx = sx * 0.03125f, cy = sy * 0.03125f, cz = sz * 0.03125f;
  float c00 = 0.f, c10 = 0.f, c20 = 0.f, c11 = 0.f, c21 = 0.f, c22 = 0.f;
  for (int k = 0; k < KNN; ++k) {
    unsigned j = idx[n * KNN + k];
    float lx = pos[j * 3 + 0] - cx;
    float ly = pos[j * 3 + 1] - cy;
    float lz = pos[j * 3 + 2] - cz;
    c00 += lx * lx; c10 += lx * ly; c20 += lx * lz;
    c11 += ly * ly; c21 += ly * lz; c22 += lz * lz;
  }
  c00 *= 0.03125f; c10 *= 0.03125f; c20 *= 0.03125f;
  c11 *= 0.03125f; c21 *= 0.03125f; c22 *= 0.03125f;
  float V[3][3];
  eigh3(c00, c10, c20, c11, c21, c22, V);
  center[n * 3 + 0] = cx; center[n * 3 + 1] = cy; center[n * 3 + 2] = cz;
  for (int i = 0; i < 3; ++i)
    for (int j2 = 0; j2 < 3; ++j2)
      Vmat[n * 9 + i * 3 + j2] = V[i][j2];
}

// ===================== kernel 3: basis + G[b,i] + 27x (64x64) matmuls =====================
#define NT 8
__global__ __launch_bounds__(256) void conv_kernel(const float* __restrict__ pos,
                                                   const float* __restrict__ chan,
                                                   const float* __restrict__ coeff,
                                                   const unsigned* __restrict__ idx,
                                                   const float* __restrict__ center,
                                                   const float* __restrict__ Vmat,
                                                   float* __restrict__ out) {
#pragma clang fp contract(off)
  __shared__ float G[NT][NBASIS][64];
  __shared__ float Tsh[NT][64];
  const int tid  = threadIdx.x;
  const int lane = tid & 63;
  const int wave = tid >> 6;
  const int n0 = blockIdx.x * NT;

  for (int rep = 0; rep < 2; ++rep) {
    const int nl = wave * 2 + rep;
    const int n = n0 + nl;
    const float cx = center[n * 3 + 0], cy = center[n * 3 + 1], cz = center[n * 3 + 2];
    const float V00 = Vmat[n * 9 + 0], V01 = Vmat[n * 9 + 1], V02 = Vmat[n * 9 + 2];
    const float V10 = Vmat[n * 9 + 3], V11 = Vmat[n * 9 + 4], V12 = Vmat[n * 9 + 5];
    const float V20 = Vmat[n * 9 + 6], V21 = Vmat[n * 9 + 7], V22 = Vmat[n * 9 + 8];
    float g[NBASIS];
#pragma unroll
    for (int b = 0; b < NBASIS; ++b) g[b] = 0.f;
    for (int k = 0; k < KNN; ++k) {
      const unsigned j = idx[n * KNN + k];
      const float lx = pos[j * 3 + 0] - cx;
      const float ly = pos[j * 3 + 1] - cy;
      const float lz = pos[j * 3 + 2] - cz;
      const float X  = lx * V00 + ly * V10 + lz * V20;
      const float Y  = lx * V01 + ly * V11 + lz * V21;
      const float Zc = lx * V02 + ly * V12 + lz * V22;
      const float r = sqrtf(((X * X + Y * Y) + Zc * Zc) + 1e-8f);
      float u = Zc / r;
      u = fminf(fmaxf(u, -0.999999f), 0.999999f);
      const float ct1 = u, ct2 = 2.f * u * u - 1.f;
      const float rho2 = X * X + Y * Y;
      const float cp1 = (rho2 > 0.f) ? (X / sqrtf(rho2)) : 1.f;
      const float cp2 = 2.f * cp1 * cp1 - 1.f;
      const float f = chan[(size_t)j * 64 + lane];
      const float pr1 = r, pr2 = r * r;
      float tc[9];
      tc[0] = 1.f; tc[1] = cp1; tc[2] = cp2;
      tc[3] = ct1; tc[4] = ct1 * cp1; tc[5] = ct1 * cp2;
      tc[6] = ct2; tc[7] = ct2 * cp1; tc[8] = ct2 * cp2;
#pragma unroll
      for (int m9 = 0; m9 < 9; ++m9) {
        g[m9]      = __builtin_fmaf(tc[m9],       f, g[m9]);
        g[9 + m9]  = __builtin_fmaf(pr1 * tc[m9], f, g[9 + m9]);
        g[18 + m9] = __builtin_fmaf(pr2 * tc[m9], f, g[18 + m9]);
      }
    }
#pragma unroll
    for (int b = 0; b < NBASIS; ++b) G[nl][b][lane] = g[b];
  }
  __syncthreads();

  float acc0 = 0.f, acc1 = 0.f;
  for (int b = 0; b < NBASIS; ++b) {
#pragma unroll 8
    for (int i = 0; i < 64; ++i) {
      const float c = coeff[(size_t)(b * 64 + i) * 64 + lane];
      acc0 = __builtin_fmaf(c, G[wave * 2 + 0][b][i], acc0);
      acc1 = __builtin_fmaf(c, G[wave * 2 + 1][b][i], acc1);
    }
  }
  __syncthreads();
  Tsh[wave * 2 + 0][lane] = acc0 * 0.03125f;
  Tsh[wave * 2 + 1][lane] = acc1 * 0.03125f;
  __syncthreads();
#pragma unroll
  for (int s = 0; s < 2; ++s) {
    const int el = tid + s * 256;
    const int o = el >> 3, nn = el & 7;
    out[(size_t)o * NPOINTS + (n0 + nn)] = Tsh[nn][o];
  }
}

// ===================== launch =====================
extern "C" void kernel_launch(void* const* d_in, const int* in_sizes, int n_in,
                              void* d_out, int out_size, void* d_ws, size_t ws_size,
                              hipStream_t stream) {
  (void)in_sizes; (void)n_in; (void)out_size; (void)ws_size;
  const float* pos   = (const float*)d_in[0];
  const float* chan  = (const float*)d_in[1];
  const float* coeff = (const float*)d_in[2];
  float* out = (float*)d_out;
  unsigned char* ws = (unsigned char*)d_ws;
  unsigned* idx  = (unsigned*)(ws);                                                 // 2 MiB
  float* center  = (float*)(ws + (size_t)NPOINTS * KNN * 4);                        // 192 KiB
  float* Vmat    = (float*)(ws + (size_t)NPOINTS * KNN * 4 + (size_t)NPOINTS * 12); // 576 KiB
  hipLaunchKernelGGL(knn_kernel,  dim3(NPOINTS / ROWS), dim3(256), 0, stream, pos, idx);
  hipLaunchKernelGGL(pca_kernel,  dim3(NPOINTS / 256),  dim3(256), 0, stream, pos, idx, center, Vmat);
  hipLaunchKernelGGL(conv_kernel, dim3(NPOINTS / NT),   dim3(256), 0, stream, pos, chan, coeff, idx, center, Vmat, out);
}

// Round 8
// 1124.719 us; speedup vs baseline: 1.9620x; 1.9620x over previous
//
#include <hip/hip_runtime.h>
#include <math.h>

#define NPOINTS 16384
#define KNN     32
#define NBASIS  27

typedef unsigned long long ull;

// ===================== helpers =====================

__device__ __forceinline__ unsigned fkey(float f) {
  // monotone order-preserving map fp32 -> uint32
  unsigned u = __float_as_uint(f);
  return (u & 0x80000000u) ? ~u : (u | 0x80000000u);
}

__device__ __forceinline__ ull shflx64(ull v, int mask) {
  int lo = __shfl_xor((int)(unsigned)(v & 0xFFFFFFFFULL), mask, 64);
  int hi = __shfl_xor((int)(unsigned)(v >> 32), mask, 64);
  return ((ull)(unsigned)hi << 32) | (ull)(unsigned)lo;
}

// ===================== faithful ssyevd(3x3) port (double arith, fp32 eps) ============

__device__ __forceinline__ void slartg_dev(double f, double g, double* c, double* s, double* r) {
#pragma clang fp contract(off)
  // LAPACK >= 3.10 convention (c >= 0)
  if (g == 0.0) { *c = 1.0; *s = 0.0; *r = f; }
  else if (f == 0.0) { *c = 0.0; *s = (g >= 0.0 ? 1.0 : -1.0); *r = fabs(g); }
  else {
    double d = sqrt(f * f + g * g);
    *c = fabs(f) / d;
    *r = (f >= 0.0) ? d : -d;
    *s = g / (*r);
  }
}

__device__ __forceinline__ void slaev2_dev(double a, double b, double c,
                                           double* rt1, double* rt2, double* cs1, double* sn1) {
#pragma clang fp contract(off)
  double sm = a + c, df = a - c, adf = fabs(df), tb = b + b, ab = fabs(tb);
  double acmx, acmn;
  if (fabs(a) > fabs(c)) { acmx = a; acmn = c; } else { acmx = c; acmn = a; }
  double rt;
  if (adf > ab)      rt = adf * sqrt(1.0 + (ab / adf) * (ab / adf));
  else if (adf < ab) rt = ab * sqrt(1.0 + (adf / ab) * (adf / ab));
  else               rt = ab * sqrt(2.0);
  int sgn1;
  if (sm < 0.0) { *rt1 = 0.5 * (sm - rt); sgn1 = -1; *rt2 = (acmx / *rt1) * acmn - (b / *rt1) * b; }
  else if (sm > 0.0) { *rt1 = 0.5 * (sm + rt); sgn1 = 1; *rt2 = (acmx / *rt1) * acmn - (b / *rt1) * b; }
  else { *rt1 = 0.5 * rt; *rt2 = -0.5 * rt; sgn1 = 1; }
  int sgn2; double cs;
  if (df >= 0.0) { cs = df + rt; sgn2 = 1; } else { cs = df - rt; sgn2 = -1; }
  double acs = fabs(cs);
  if (acs > ab) { double ct = -tb / cs; double sn = 1.0 / sqrt(1.0 + ct * ct); *sn1 = sn; *cs1 = ct * sn; }
  else {
    if (ab == 0.0) { *cs1 = 1.0; *sn1 = 0.0; }
    else { double tn = -cs / tb; double c1 = 1.0 / sqrt(1.0 + tn * tn); *cs1 = c1; *sn1 = tn * c1; }
  }
  if (sgn1 == sgn2) { double tn = *cs1; *cs1 = -(*sn1); *sn1 = tn; }
}

// Input: lower triangle of symmetric 3x3 (fp32 cov). Output: V columns in DESCENDING
// eigenvalue order (LAPACK ascending, reversed) = np/jnp eigh + [:, :, ::-1].
__device__ void eigh3(float A00, float A10, float A20, float A11, float A21, float A22,
                      float V[3][3]) {
#pragma clang fp contract(off)
  const double EPS    = 5.9604644775390625e-08;   // fp32 slamch('E')
  const double EPS2   = EPS * EPS;
  const double SAFMIN = 1.1754943508222875e-38;   // fp32 slamch('S')
  double d[3], e[2];
  double tau = 0.0, v2 = 0.0;
  // ---- ssytd2 (uplo='L'), single Householder on [A10; A20]
  {
    double alpha = (double)A10, x = (double)A20;
    double a11 = (double)A11, a21 = (double)A21, a22 = (double)A22;
    double beta;
    if (x == 0.0) { tau = 0.0; v2 = 0.0; beta = alpha; }
    else {
      double nrm = sqrt(alpha * alpha + x * x);          // slapy2
      beta = (alpha >= 0.0) ? -nrm : nrm;                // -sign(nrm, alpha)
      tau = (beta - alpha) / beta;
      v2 = x / (alpha - beta);
    }
    if (tau != 0.0) {
      double w0 = tau * (a11 + a21 * v2);
      double w1 = tau * (a21 + a22 * v2);
      double cc = 0.5 * tau * (w0 + w1 * v2);
      w0 -= cc; w1 -= cc * v2;
      a11 -= 2.0 * w0;
      a21 -= (v2 * w0 + w1);
      a22 -= 2.0 * v2 * w1;
    }
    d[0] = (double)A00; d[1] = a11; d[2] = a22;
    e[0] = beta; e[1] = a21;
  }
  double Z[3][3] = { {1.0, 0.0, 0.0}, {0.0, 1.0, 0.0}, {0.0, 0.0, 1.0} };
  // ---- ssteqr('I', n=3)
  {
    int l1 = 1, jtot = 0;
    const int nmaxit = 90;
    double wc[2], wsn[2];
    while (l1 <= 3) {
      if (l1 > 1) e[l1 - 2] = 0.0;
      int m = 3;
      for (int mm = l1; mm <= 2; ++mm) {
        double tst = fabs(e[mm - 1]);
        if (tst == 0.0) { m = mm; break; }
        if (tst <= (sqrt(fabs(d[mm - 1])) * sqrt(fabs(d[mm]))) * EPS) { e[mm - 1] = 0.0; m = mm; break; }
      }
      int l = l1, lsv = l, lend = m, lendsv = lend;
      l1 = m + 1;
      if (lend == l) continue;
      double anorm = 0.0;
      for (int i = l; i <= lend; ++i)     anorm = fmax(anorm, fabs(d[i - 1]));
      for (int i = l; i <= lend - 1; ++i) anorm = fmax(anorm, fabs(e[i - 1]));
      if (anorm == 0.0) continue;
      if (fabs(d[lend - 1]) < fabs(d[l - 1])) { lend = lsv; l = lendsv; }
      if (lend > l) {
        // ===== QL =====
        bool done = false;
        while (!done) {
          int mq = lend;
          for (int mm = l; mm <= lend - 1; ++mm) {
            double tst = e[mm - 1] * e[mm - 1];
            if (tst <= (EPS2 * fabs(d[mm - 1])) * fabs(d[mm]) + SAFMIN) { mq = mm; break; }
          }
          if (mq < lend) e[mq - 1] = 0.0;
          double p = d[l - 1];
          if (mq == l) { d[l - 1] = p; ++l; if (l > lend) done = true; continue; }
          if (mq == l + 1) {
            double rt1, rt2, cc, ssn;
            slaev2_dev(d[l - 1], e[l - 1], d[l], &rt1, &rt2, &cc, &ssn);
            for (int i = 0; i < 3; ++i) {
              double t = Z[i][l];
              Z[i][l]     = cc * t - ssn * Z[i][l - 1];
              Z[i][l - 1] = ssn * t + cc * Z[i][l - 1];
            }
            d[l - 1] = rt1; d[l] = rt2; e[l - 1] = 0.0;
            l += 2; if (l > lend) done = true; continue;
          }
          if (jtot >= nmaxit) break;
          ++jtot;
          double g = (d[l] - p) / (2.0 * e[l - 1]);
          double r = sqrt(g * g + 1.0);
          g = d[mq - 1] - p + e[l - 1] / (g + ((g >= 0.0) ? r : -r));
          double ssn = 1.0, cc = 1.0;
          p = 0.0;
          for (int i = mq - 1; i >= l; --i) {
            double f = ssn * e[i - 1], b = cc * e[i - 1];
            slartg_dev(g, f, &cc, &ssn, &r);
            if (i != mq - 1) e[i] = r;
            g = d[i] - p;
            r = (d[i - 1] - g) * ssn + 2.0 * cc * b;
            p = ssn * r;
            d[i] = g + p;
            g = cc * r - b;
            wc[i - 1] = cc; wsn[i - 1] = -ssn;
          }
          for (int j = mq - 1; j >= l; --j) {
            double cj = wc[j - 1], sj = wsn[j - 1];
            for (int i = 0; i < 3; ++i) {
              double t = Z[i][j];
              Z[i][j]     = cj * t - sj * Z[i][j - 1];
              Z[i][j - 1] = sj * t + cj * Z[i][j - 1];
            }
          }
          d[l - 1] -= p; e[l - 1] = g;
        }
      } else {
        // ===== QR =====
        bool done = false;
        while (!done) {
          int mq = lend;
          for (int mm = l; mm >= lend + 1; --mm) {
            double tst = e[mm - 2] * e[mm - 2];
            if (tst <= (EPS2 * fabs(d[mm - 1])) * fabs(d[mm - 2]) + SAFMIN) { mq = mm; break; }
          }
          if (mq > lend) e[mq - 2] = 0.0;
          double p = d[l - 1];
          if (mq == l) { d[l - 1] = p; --l; if (l < lend) done = true; continue; }
          if (mq == l - 1) {
            double rt1, rt2, cc, ssn;
            slaev2_dev(d[l - 2], e[l - 2], d[l - 1], &rt1, &rt2, &cc, &ssn);
            for (int i = 0; i < 3; ++i) {
              double t = Z[i][l - 1];
              Z[i][l - 1] = cc * t - ssn * Z[i][l - 2];
              Z[i][l - 2] = ssn * t + cc * Z[i][l - 2];
            }
            d[l - 2] = rt1; d[l - 1] = rt2; e[l - 2] = 0.0;
            l -= 2; if (l < lend) done = true; continue;
          }
          if (jtot >= nmaxit) break;
          ++jtot;
          double g = (d[l - 2] - p) / (2.0 * e[l - 2]);
          double r = sqrt(g * g + 1.0);
          g = d[mq - 1] - p + e[l - 2] / (g + ((g >= 0.0) ? r : -r));
          double ssn = 1.0, cc = 1.0;
          p = 0.0;
          for (int i = mq; i <= l - 1; ++i) {
            double f = ssn * e[i - 1], b = cc * e[i - 1];
            slartg_dev(g, f, &cc, &ssn, &r);
            if (i != mq) e[i - 2] = r;
            g = d[i - 1] - p;
            r = (d[i] - g) * ssn + 2.0 * cc * b;
            p = ssn * r;
            d[i - 1] = g + p;
            g = cc * r - b;
            wc[i - 1] = cc; wsn[i - 1] = ssn;
          }
          for (int j = mq; j <= l - 1; ++j) {
            double cj = wc[j - 1], sj = wsn[j - 1];
            for (int i = 0; i < 3; ++i) {
              double t = Z[i][j];
              Z[i][j]     = cj * t - sj * Z[i][j - 1];
              Z[i][j - 1] = sj * t + cj * Z[i][j - 1];
            }
          }
          d[l - 1] -= p; e[l - 2] = g;
        }
      }
    }
    // ---- ascending selection sort with column swaps (as in ssteqr)
    for (int ii = 2; ii <= 3; ++ii) {
      int i0 = ii - 1, k = i0;
      double p = d[i0 - 1];
      for (int j = ii; j <= 3; ++j) if (d[j - 1] < p) { k = j; p = d[j - 1]; }
      if (k != i0) {
        d[k - 1] = d[i0 - 1]; d[i0 - 1] = p;
        for (int rr = 0; rr < 3; ++rr) { double t = Z[rr][i0 - 1]; Z[rr][i0 - 1] = Z[rr][k - 1]; Z[rr][k - 1] = t; }
      }
    }
  }
  // ---- sormtr: Z := H1 * Z
  if (tau != 0.0) {
    for (int j = 0; j < 3; ++j) {
      double w = Z[1][j] + v2 * Z[2][j];
      Z[1][j] -= tau * w;
      Z[2][j] -= tau * v2 * w;
    }
  }
  for (int i = 0; i < 3; ++i)
    for (int j = 0; j < 3; ++j)
      V[i][j] = (float)Z[i][2 - j];
}

// ===================== kernel 0: pack pos -> float4 {x,y,z,sq} =====================
__global__ __launch_bounds__(256) void pack_kernel(const float* __restrict__ pos,
                                                   float4* __restrict__ pos4) {
#pragma clang fp contract(off)
  int i = blockIdx.x * 256 + threadIdx.x;
  if (i < NPOINTS) {
    float x = pos[3 * i + 0], y = pos[3 * i + 1], z = pos[3 * i + 2];
    float sq = (x * x + y * y) + z * z;   // XLA reduce order (same as r6)
    pos4[i] = make_float4(x, y, z, sq);
  }
}

// ===================== kernel 1: exact KNN, streaming per-lane top-8 =====================
// Selection order: C = (fkey(d2) << 32) | (0xFFFFFFFF - idx)  -- strict total order.
// 32 smallest C == r6-verified semantics (key asc, ties -> HIGHER index first).
// Chain A d2: mdot = fma(z,z', fma(y,y', x*x')); d2 = (sq_i + sq_j) - 2*mdot.  (unchanged)
#define WPB 4   // waves (rows) per block

__global__ __launch_bounds__(256) void knn_kernel(const float4* __restrict__ pos4,
                                                  unsigned* __restrict__ idx_out) {
#pragma clang fp contract(off)
  __shared__ ull pool[WPB][512];   // per-row: 64 lanes x 8 sorted C
  __shared__ ull sel[WPB][KNN];    // per-row: selected 32 (ascending C)
  const int tid  = threadIdx.x;
  const int lane = tid & 63;
  const int wave = tid >> 6;
  const int row  = blockIdx.x * WPB + wave;

  const float4 rp = pos4[row];
  const float rx = rp.x, ry = rp.y, rz = rp.z, rq = rp.w;

  // per-lane 8 smallest C, sorted ascending s0<=...<=s7
  ull s0 = ~0ULL, s1 = ~0ULL, s2 = ~0ULL, s3 = ~0ULL,
      s4 = ~0ULL, s5 = ~0ULL, s6 = ~0ULL, s7 = ~0ULL;

  for (int ch = 0; ch < NPOINTS / 64; ++ch) {
    const int j = ch * 64 + lane;
    const float4 p = pos4[j];
    const float mdot = __builtin_fmaf(rz, p.z, __builtin_fmaf(ry, p.y, rx * p.x));
    const float d2 = (rq + p.w) - 2.0f * mdot;
    const unsigned key = fkey(d2);
    const ull C = ((ull)key << 32) | (ull)(0xFFFFFFFFu - (unsigned)j);
    if (C < s7) {
      s7 = C;
      if (s7 < s6) { ull t = s6; s6 = s7; s7 = t; }
      if (s6 < s5) { ull t = s5; s5 = s6; s6 = t; }
      if (s5 < s4) { ull t = s4; s4 = s5; s5 = t; }
      if (s4 < s3) { ull t = s3; s3 = s4; s4 = t; }
      if (s3 < s2) { ull t = s2; s2 = s3; s3 = t; }
      if (s2 < s1) { ull t = s1; s1 = s2; s2 = t; }
      if (s1 < s0) { ull t = s0; s0 = s1; s1 = t; }
    }
  }

  // pool layout [k*64 + lane] (conflict-friendly)
  pool[wave][0 * 64 + lane] = s0;
  pool[wave][1 * 64 + lane] = s1;
  pool[wave][2 * 64 + lane] = s2;
  pool[wave][3 * 64 + lane] = s3;
  pool[wave][4 * 64 + lane] = s4;
  pool[wave][5 * 64 + lane] = s5;
  pool[wave][6 * 64 + lane] = s6;
  pool[wave][7 * 64 + lane] = s7;
  // waves are independent (each owns its pool row); in-wave LDS visibility only
  __builtin_amdgcn_s_waitcnt(0);   // lgkmcnt(0) for our own ds_writes

  // wave-parallel extraction of the 32 smallest
  int head = 0;
  ull Tcand = 0;
  for (int it = 0; it < KNN; ++it) {
    ull v = (head < 8) ? pool[wave][head * 64 + lane] : ~0ULL;
    ull m = v;
    for (int off = 1; off < 64; off <<= 1) {
      ull o = shflx64(m, off);
      m = (o < m) ? o : m;
    }
    ull win = __ballot(v == m);
    int wl = __ffsll((long long)win) - 1;
    if (lane == wl) ++head;
    if (lane == 0) sel[wave][it] = m;
    Tcand = m;
  }

  // completeness certificate: every evicted value >= its lane's s7.
  // If s7 >= Tcand for all lanes, no true-top-32 member was ever evicted.
  ull bad = __ballot(s7 < Tcand);
  if (bad != 0ULL) {
    // exact serial fallback for this row (rare: P ~ 2e-6 per row)
    if (lane == 0) {
      int cnt = 0;
      for (int j = 0; j < NPOINTS; ++j) {
        const float4 p = pos4[j];
        const float mdot = __builtin_fmaf(rz, p.z, __builtin_fmaf(ry, p.y, rx * p.x));
        const float d2 = (rq + p.w) - 2.0f * mdot;
        const unsigned key = fkey(d2);
        const ull C = ((ull)key << 32) | (ull)(0xFFFFFFFFu - (unsigned)j);
        if (cnt < KNN) {
          int b = cnt - 1;
          while (b >= 0 && sel[wave][b] > C) { sel[wave][b + 1] = sel[wave][b]; --b; }
          sel[wave][b + 1] = C;
          ++cnt;
        } else if (C < sel[wave][KNN - 1]) {
          int b = KNN - 2;
          while (b >= 0 && sel[wave][b] > C) { sel[wave][b + 1] = sel[wave][b]; --b; }
          sel[wave][b + 1] = C;
        }
      }
    }
  }

  // finalize (lane 0 per row): decompose, sort by (key asc, idx asc), emit
  if (lane == 0) {
    unsigned kk[KNN], ii[KNN];
    for (int a = 0; a < KNN; ++a) {
      ull C = sel[wave][a];
      kk[a] = (unsigned)(C >> 32);
      ii[a] = 0xFFFFFFFFu - (unsigned)(C & 0xFFFFFFFFULL);
    }
    for (int a = 1; a < KNN; ++a) {
      unsigned ka = kk[a], ia = ii[a];
      int b = a - 1;
      while (b >= 0 && (kk[b] > ka || (kk[b] == ka && ii[b] > ia))) {
        kk[b + 1] = kk[b]; ii[b + 1] = ii[b]; --b;
      }
      kk[b + 1] = ka; ii[b + 1] = ia;
    }
    unsigned ob = (unsigned)row * KNN;
    for (int a = 0; a < KNN; ++a) idx_out[ob + a] = ii[a];
  }
}

// ===================== kernel 2: mean + cov + eigh per point (fp32) =====================
__global__ __launch_bounds__(256) void pca_kernel(const float* __restrict__ pos,
                                                  const unsigned* __restrict__ idx,
                                                  float* __restrict__ center,
                                                  float* __restrict__ Vmat) {
#pragma clang fp contract(off)
  int n = blockIdx.x * 256 + threadIdx.x;
  if (n >= NPOINTS) return;
  float sx = 0.f, sy = 0.f, sz = 0.f;
  for (int k = 0; k < KNN; ++k) {
    unsigned j = idx[n * KNN + k];
    sx += pos[j * 3 + 0];
    sy += pos[j * 3 + 1];
    sz += pos[j * 3 + 2];
  }
  float cx = sx * 0.03125f, cy = sy * 0.03125f, cz = sz * 0.03125f;
  float c00 = 0.f, c10 = 0.f, c20 = 0.f, c11 = 0.f, c21 = 0.f, c22 = 0.f;
  for (int k = 0; k < KNN; ++k) {
    unsigned j = idx[n * KNN + k];
    float lx = pos[j * 3 + 0] - cx;
    float ly = pos[j * 3 + 1] - cy;
    float lz = pos[j * 3 + 2] - cz;
    c00 += lx * lx; c10 += lx * ly; c20 += lx * lz;
    c11 += ly * ly; c21 += ly * lz; c22 += lz * lz;
  }
  c00 *= 0.03125f; c10 *= 0.03125f; c20 *= 0.03125f;
  c11 *= 0.03125f; c21 *= 0.03125f; c22 *= 0.03125f;
  float V[3][3];
  eigh3(c00, c10, c20, c11, c21, c22, V);
  center[n * 3 + 0] = cx; center[n * 3 + 1] = cy; center[n * 3 + 2] = cz;
  for (int i = 0; i < 3; ++i)
    for (int j2 = 0; j2 < 3; ++j2)
      Vmat[n * 9 + i * 3 + j2] = V[i][j2];
}

// ===================== kernel 3: basis + G[b,i] + 27x (64x64) matmuls =====================
#define NT 8
__global__ __launch_bounds__(256) void conv_kernel(const float* __restrict__ pos,
                                                   const float* __restrict__ chan,
                                                   const float* __restrict__ coeff,
                                                   const unsigned* __restrict__ idx,
                                                   const float* __restrict__ center,
                                                   const float* __restrict__ Vmat,
                                                   float* __restrict__ out) {
#pragma clang fp contract(off)
  __shared__ float G[NT][NBASIS][64];
  __shared__ float Tsh[NT][64];
  const int tid  = threadIdx.x;
  const int lane = tid & 63;
  const int wave = tid >> 6;
  const int n0 = blockIdx.x * NT;

  for (int rep = 0; rep < 2; ++rep) {
    const int nl = wave * 2 + rep;
    const int n = n0 + nl;
    const float cx = center[n * 3 + 0], cy = center[n * 3 + 1], cz = center[n * 3 + 2];
    const float V00 = Vmat[n * 9 + 0], V01 = Vmat[n * 9 + 1], V02 = Vmat[n * 9 + 2];
    const float V10 = Vmat[n * 9 + 3], V11 = Vmat[n * 9 + 4], V12 = Vmat[n * 9 + 5];
    const float V20 = Vmat[n * 9 + 6], V21 = Vmat[n * 9 + 7], V22 = Vmat[n * 9 + 8];
    float g[NBASIS];
#pragma unroll
    for (int b = 0; b < NBASIS; ++b) g[b] = 0.f;
    for (int k = 0; k < KNN; ++k) {
      const unsigned j = idx[n * KNN + k];
      const float lx = pos[j * 3 + 0] - cx;
      const float ly = pos[j * 3 + 1] - cy;
      const float lz = pos[j * 3 + 2] - cz;
      const float X  = lx * V00 + ly * V10 + lz * V20;
      const float Y  = lx * V01 + ly * V11 + lz * V21;
      const float Zc = lx * V02 + ly * V12 + lz * V22;
      const float r = sqrtf(((X * X + Y * Y) + Zc * Zc) + 1e-8f);
      float u = Zc / r;
      u = fminf(fmaxf(u, -0.999999f), 0.999999f);
      const float ct1 = u, ct2 = 2.f * u * u - 1.f;
      const float rho2 = X * X + Y * Y;
      const float cp1 = (rho2 > 0.f) ? (X / sqrtf(rho2)) : 1.f;
      const float cp2 = 2.f * cp1 * cp1 - 1.f;
      const float f = chan[(size_t)j * 64 + lane];
      const float pr1 = r, pr2 = r * r;
      float tc[9];
      tc[0] = 1.f; tc[1] = cp1; tc[2] = cp2;
      tc[3] = ct1; tc[4] = ct1 * cp1; tc[5] = ct1 * cp2;
      tc[6] = ct2; tc[7] = ct2 * cp1; tc[8] = ct2 * cp2;
#pragma unroll
      for (int m9 = 0; m9 < 9; ++m9) {
        g[m9]      = __builtin_fmaf(tc[m9],       f, g[m9]);
        g[9 + m9]  = __builtin_fmaf(pr1 * tc[m9], f, g[9 + m9]);
        g[18 + m9] = __builtin_fmaf(pr2 * tc[m9], f, g[18 + m9]);
      }
    }
#pragma unroll
    for (int b = 0; b < NBASIS; ++b) G[nl][b][lane] = g[b];
  }
  __syncthreads();

  float acc0 = 0.f, acc1 = 0.f;
  for (int b = 0; b < NBASIS; ++b) {
#pragma unroll 8
    for (int i = 0; i < 64; ++i) {
      const float c = coeff[(size_t)(b * 64 + i) * 64 + lane];
      acc0 = __builtin_fmaf(c, G[wave * 2 + 0][b][i], acc0);
      acc1 = __builtin_fmaf(c, G[wave * 2 + 1][b][i], acc1);
    }
  }
  __syncthreads();
  Tsh[wave * 2 + 0][lane] = acc0 * 0.03125f;
  Tsh[wave * 2 + 1][lane] = acc1 * 0.03125f;
  __syncthreads();
#pragma unroll
  for (int s = 0; s < 2; ++s) {
    const int el = tid + s * 256;
    const int o = el >> 3, nn = el & 7;
    out[(size_t)o * NPOINTS + (n0 + nn)] = Tsh[nn][o];
  }
}

// ===================== launch =====================
extern "C" void kernel_launch(void* const* d_in, const int* in_sizes, int n_in,
                              void* d_out, int out_size, void* d_ws, size_t ws_size,
                              hipStream_t stream) {
  (void)in_sizes; (void)n_in; (void)out_size; (void)ws_size;
  const float* pos   = (const float*)d_in[0];
  const float* chan  = (const float*)d_in[1];
  const float* coeff = (const float*)d_in[2];
  float* out = (float*)d_out;
  unsigned char* ws = (unsigned char*)d_ws;
  float4*   pos4   = (float4*)(ws);                                    // 256 KiB
  unsigned* idx    = (unsigned*)(ws + (size_t)NPOINTS * 16);           // 2 MiB
  float*    center = (float*)(ws + (size_t)NPOINTS * 16 + (size_t)NPOINTS * KNN * 4);          // 192 KiB
  float*    Vmat   = (float*)(ws + (size_t)NPOINTS * 16 + (size_t)NPOINTS * KNN * 4
                              + (size_t)NPOINTS * 12);                 // 576 KiB
  hipLaunchKernelGGL(pack_kernel, dim3(NPOINTS / 256),  dim3(256), 0, stream, pos, pos4);
  hipLaunchKernelGGL(knn_kernel,  dim3(NPOINTS / WPB),  dim3(256), 0, stream, pos4, idx);
  hipLaunchKernelGGL(pca_kernel,  dim3(NPOINTS / 256),  dim3(256), 0, stream, pos, idx, center, Vmat);
  hipLaunchKernelGGL(conv_kernel, dim3(NPOINTS / NT),   dim3(256), 0, stream, pos, chan, coeff, idx, center, Vmat, out);
}

// Round 9
// 1025.430 us; speedup vs baseline: 2.1519x; 1.0968x over previous
//
#include <hip/hip_runtime.h>
#include <math.h>

#define NPOINTS 16384
#define KNN     32
#define NBASIS  27

typedef unsigned long long ull;

// ===================== helpers =====================

__device__ __forceinline__ unsigned fkey(float f) {
  // monotone order-preserving map fp32 -> uint32 (3 VALU: ashr, or, xor)
  unsigned u = __float_as_uint(f);
  unsigned m = (unsigned)((int)u >> 31) | 0x80000000u;
  return u ^ m;
}

__device__ __forceinline__ ull shflx64(ull v, int mask) {
  int lo = __shfl_xor((int)(unsigned)(v & 0xFFFFFFFFULL), mask, 64);
  int hi = __shfl_xor((int)(unsigned)(v >> 32), mask, 64);
  return ((ull)(unsigned)hi << 32) | (ull)(unsigned)lo;
}

// ===================== faithful ssyevd(3x3) port (double arith, fp32 eps) ============

__device__ __forceinline__ void slartg_dev(double f, double g, double* c, double* s, double* r) {
#pragma clang fp contract(off)
  // LAPACK >= 3.10 convention (c >= 0)
  if (g == 0.0) { *c = 1.0; *s = 0.0; *r = f; }
  else if (f == 0.0) { *c = 0.0; *s = (g >= 0.0 ? 1.0 : -1.0); *r = fabs(g); }
  else {
    double d = sqrt(f * f + g * g);
    *c = fabs(f) / d;
    *r = (f >= 0.0) ? d : -d;
    *s = g / (*r);
  }
}

__device__ __forceinline__ void slaev2_dev(double a, double b, double c,
                                           double* rt1, double* rt2, double* cs1, double* sn1) {
#pragma clang fp contract(off)
  double sm = a + c, df = a - c, adf = fabs(df), tb = b + b, ab = fabs(tb);
  double acmx, acmn;
  if (fabs(a) > fabs(c)) { acmx = a; acmn = c; } else { acmx = c; acmn = a; }
  double rt;
  if (adf > ab)      rt = adf * sqrt(1.0 + (ab / adf) * (ab / adf));
  else if (adf < ab) rt = ab * sqrt(1.0 + (adf / ab) * (adf / ab));
  else               rt = ab * sqrt(2.0);
  int sgn1;
  if (sm < 0.0) { *rt1 = 0.5 * (sm - rt); sgn1 = -1; *rt2 = (acmx / *rt1) * acmn - (b / *rt1) * b; }
  else if (sm > 0.0) { *rt1 = 0.5 * (sm + rt); sgn1 = 1; *rt2 = (acmx / *rt1) * acmn - (b / *rt1) * b; }
  else { *rt1 = 0.5 * rt; *rt2 = -0.5 * rt; sgn1 = 1; }
  int sgn2; double cs;
  if (df >= 0.0) { cs = df + rt; sgn2 = 1; } else { cs = df - rt; sgn2 = -1; }
  double acs = fabs(cs);
  if (acs > ab) { double ct = -tb / cs; double sn = 1.0 / sqrt(1.0 + ct * ct); *sn1 = sn; *cs1 = ct * sn; }
  else {
    if (ab == 0.0) { *cs1 = 1.0; *sn1 = 0.0; }
    else { double tn = -cs / tb; double c1 = 1.0 / sqrt(1.0 + tn * tn); *cs1 = c1; *sn1 = tn * c1; }
  }
  if (sgn1 == sgn2) { double tn = *cs1; *cs1 = -(*sn1); *sn1 = tn; }
}

// Input: lower triangle of symmetric 3x3 (fp32 cov). Output: V columns in DESCENDING
// eigenvalue order (LAPACK ascending, reversed) = np/jnp eigh + [:, :, ::-1].
__device__ void eigh3(float A00, float A10, float A20, float A11, float A21, float A22,
                      float V[3][3]) {
#pragma clang fp contract(off)
  const double EPS    = 5.9604644775390625e-08;   // fp32 slamch('E')
  const double EPS2   = EPS * EPS;
  const double SAFMIN = 1.1754943508222875e-38;   // fp32 slamch('S')
  double d[3], e[2];
  double tau = 0.0, v2 = 0.0;
  // ---- ssytd2 (uplo='L'), single Householder on [A10; A20]
  {
    double alpha = (double)A10, x = (double)A20;
    double a11 = (double)A11, a21 = (double)A21, a22 = (double)A22;
    double beta;
    if (x == 0.0) { tau = 0.0; v2 = 0.0; beta = alpha; }
    else {
      double nrm = sqrt(alpha * alpha + x * x);          // slapy2
      beta = (alpha >= 0.0) ? -nrm : nrm;                // -sign(nrm, alpha)
      tau = (beta - alpha) / beta;
      v2 = x / (alpha - beta);
    }
    if (tau != 0.0) {
      double w0 = tau * (a11 + a21 * v2);
      double w1 = tau * (a21 + a22 * v2);
      double cc = 0.5 * tau * (w0 + w1 * v2);
      w0 -= cc; w1 -= cc * v2;
      a11 -= 2.0 * w0;
      a21 -= (v2 * w0 + w1);
      a22 -= 2.0 * v2 * w1;
    }
    d[0] = (double)A00; d[1] = a11; d[2] = a22;
    e[0] = beta; e[1] = a21;
  }
  double Z[3][3] = { {1.0, 0.0, 0.0}, {0.0, 1.0, 0.0}, {0.0, 0.0, 1.0} };
  // ---- ssteqr('I', n=3)
  {
    int l1 = 1, jtot = 0;
    const int nmaxit = 90;
    double wc[2], wsn[2];
    while (l1 <= 3) {
      if (l1 > 1) e[l1 - 2] = 0.0;
      int m = 3;
      for (int mm = l1; mm <= 2; ++mm) {
        double tst = fabs(e[mm - 1]);
        if (tst == 0.0) { m = mm; break; }
        if (tst <= (sqrt(fabs(d[mm - 1])) * sqrt(fabs(d[mm]))) * EPS) { e[mm - 1] = 0.0; m = mm; break; }
      }
      int l = l1, lsv = l, lend = m, lendsv = lend;
      l1 = m + 1;
      if (lend == l) continue;
      double anorm = 0.0;
      for (int i = l; i <= lend; ++i)     anorm = fmax(anorm, fabs(d[i - 1]));
      for (int i = l; i <= lend - 1; ++i) anorm = fmax(anorm, fabs(e[i - 1]));
      if (anorm == 0.0) continue;
      if (fabs(d[lend - 1]) < fabs(d[l - 1])) { lend = lsv; l = lendsv; }
      if (lend > l) {
        // ===== QL =====
        bool done = false;
        while (!done) {
          int mq = lend;
          for (int mm = l; mm <= lend - 1; ++mm) {
            double tst = e[mm - 1] * e[mm - 1];
            if (tst <= (EPS2 * fabs(d[mm - 1])) * fabs(d[mm]) + SAFMIN) { mq = mm; break; }
          }
          if (mq < lend) e[mq - 1] = 0.0;
          double p = d[l - 1];
          if (mq == l) { d[l - 1] = p; ++l; if (l > lend) done = true; continue; }
          if (mq == l + 1) {
            double rt1, rt2, cc, ssn;
            slaev2_dev(d[l - 1], e[l - 1], d[l], &rt1, &rt2, &cc, &ssn);
            for (int i = 0; i < 3; ++i) {
              double t = Z[i][l];
              Z[i][l]     = cc * t - ssn * Z[i][l - 1];
              Z[i][l - 1] = ssn * t + cc * Z[i][l - 1];
            }
            d[l - 1] = rt1; d[l] = rt2; e[l - 1] = 0.0;
            l += 2; if (l > lend) done = true; continue;
          }
          if (jtot >= nmaxit) break;
          ++jtot;
          double g = (d[l] - p) / (2.0 * e[l - 1]);
          double r = sqrt(g * g + 1.0);
          g = d[mq - 1] - p + e[l - 1] / (g + ((g >= 0.0) ? r : -r));
          double ssn = 1.0, cc = 1.0;
          p = 0.0;
          for (int i = mq - 1; i >= l; --i) {
            double f = ssn * e[i - 1], b = cc * e[i - 1];
            slartg_dev(g, f, &cc, &ssn, &r);
            if (i != mq - 1) e[i] = r;
            g = d[i] - p;
            r = (d[i - 1] - g) * ssn + 2.0 * cc * b;
            p = ssn * r;
            d[i] = g + p;
            g = cc * r - b;
            wc[i - 1] = cc; wsn[i - 1] = -ssn;
          }
          for (int j = mq - 1; j >= l; --j) {
            double cj = wc[j - 1], sj = wsn[j - 1];
            for (int i = 0; i < 3; ++i) {
              double t = Z[i][j];
              Z[i][j]     = cj * t - sj * Z[i][j - 1];
              Z[i][j - 1] = sj * t + cj * Z[i][j - 1];
            }
          }
          d[l - 1] -= p; e[l - 1] = g;
        }
      } else {
        // ===== QR =====
        bool done = false;
        while (!done) {
          int mq = lend;
          for (int mm = l; mm >= lend + 1; --mm) {
            double tst = e[mm - 2] * e[mm - 2];
            if (tst <= (EPS2 * fabs(d[mm - 1])) * fabs(d[mm - 2]) + SAFMIN) { mq = mm; break; }
          }
          if (mq > lend) e[mq - 2] = 0.0;
          double p = d[l - 1];
          if (mq == l) { d[l - 1] = p; --l; if (l < lend) done = true; continue; }
          if (mq == l - 1) {
            double rt1, rt2, cc, ssn;
            slaev2_dev(d[l - 2], e[l - 2], d[l - 1], &rt1, &rt2, &cc, &ssn);
            for (int i = 0; i < 3; ++i) {
              double t = Z[i][l - 1];
              Z[i][l - 1] = cc * t - ssn * Z[i][l - 2];
              Z[i][l - 2] = ssn * t + cc * Z[i][l - 2];
            }
            d[l - 2] = rt1; d[l - 1] = rt2; e[l - 2] = 0.0;
            l -= 2; if (l < lend) done = true; continue;
          }
          if (jtot >= nmaxit) break;
          ++jtot;
          double g = (d[l - 2] - p) / (2.0 * e[l - 2]);
          double r = sqrt(g * g + 1.0);
          g = d[mq - 1] - p + e[l - 2] / (g + ((g >= 0.0) ? r : -r));
          double ssn = 1.0, cc = 1.0;
          p = 0.0;
          for (int i = mq; i <= l - 1; ++i) {
            double f = ssn * e[i - 1], b = cc * e[i - 1];
            slartg_dev(g, f, &cc, &ssn, &r);
            if (i != mq) e[i - 2] = r;
            g = d[i - 1] - p;
            r = (d[i] - g) * ssn + 2.0 * cc * b;
            p = ssn * r;
            d[i - 1] = g + p;
            g = cc * r - b;
            wc[i - 1] = cc; wsn[i - 1] = ssn;
          }
          for (int j = mq; j <= l - 1; ++j) {
            double cj = wc[j - 1], sj = wsn[j - 1];
            for (int i = 0; i < 3; ++i) {
              double t = Z[i][j];
              Z[i][j]     = cj * t - sj * Z[i][j - 1];
              Z[i][j - 1] = sj * t + cj * Z[i][j - 1];
            }
          }
          d[l - 1] -= p; e[l - 2] = g;
        }
      }
    }
    // ---- ascending selection sort with column swaps (as in ssteqr)
    for (int ii = 2; ii <= 3; ++ii) {
      int i0 = ii - 1, k = i0;
      double p = d[i0 - 1];
      for (int j = ii; j <= 3; ++j) if (d[j - 1] < p) { k = j; p = d[j - 1]; }
      if (k != i0) {
        d[k - 1] = d[i0 - 1]; d[i0 - 1] = p;
        for (int rr = 0; rr < 3; ++rr) { double t = Z[rr][i0 - 1]; Z[rr][i0 - 1] = Z[rr][k - 1]; Z[rr][k - 1] = t; }
      }
    }
  }
  // ---- sormtr: Z := H1 * Z
  if (tau != 0.0) {
    for (int j = 0; j < 3; ++j) {
      double w = Z[1][j] + v2 * Z[2][j];
      Z[1][j] -= tau * w;
      Z[2][j] -= tau * v2 * w;
    }
  }
  for (int i = 0; i < 3; ++i)
    for (int j = 0; j < 3; ++j)
      V[i][j] = (float)Z[i][2 - j];
}

// ===================== kernel 0: pack pos -> float4 {x,y,z,sq} =====================
__global__ __launch_bounds__(256) void pack_kernel(const float* __restrict__ pos,
                                                   float4* __restrict__ pos4) {
#pragma clang fp contract(off)
  int i = blockIdx.x * 256 + threadIdx.x;
  if (i < NPOINTS) {
    float x = pos[3 * i + 0], y = pos[3 * i + 1], z = pos[3 * i + 2];
    float sq = (x * x + y * y) + z * z;   // XLA reduce order (same as r6)
    pos4[i] = make_float4(x, y, z, sq);
  }
}

// ===================== kernel 1: exact KNN, threshold + compact =====================
// Order: C = (fkey(d2) << 32) | (0xFFFFFFFF - idx). 32 smallest C == r6-verified
// semantics (key asc, ties -> HIGHER index first). Chain-A d2 unchanged.
// Phase A: branchless per-lane top-2 of 32-bit keys -> pool(128) -> Tt = pool's
//   32nd smallest >= true T32 (subset order-stat bound).
// Phase B: compact all {key <= Tt} (superset of the true top-32) -> exact select.
#define WPB 4    // rows per block (1 per wave)
#define CAP 128  // candidate capacity per row (overflow P ~ 0; serial fallback kept)

__global__ __launch_bounds__(256) void knn_kernel(const float4* __restrict__ pos4,
                                                  unsigned* __restrict__ idx_out) {
#pragma clang fp contract(off)
  __shared__ ull cand[WPB][CAP];
  __shared__ ull sel[WPB][KNN];
  const int tid  = threadIdx.x;
  const int lane = tid & 63;
  const int wave = tid >> 6;
  const int row  = blockIdx.x * WPB + wave;

  const float4 rp = pos4[row];
  const float rx = rp.x, ry = rp.y, rz = rp.z, rq = rp.w;

  // ---- phase A: branchless per-lane top-2 keys ----
  unsigned k1 = 0xFFFFFFFFu, k2 = 0xFFFFFFFFu;
  for (int ch = 0; ch < NPOINTS / 64; ++ch) {
    const int j = ch * 64 + lane;
    const float4 p = pos4[j];
    const float mdot = __builtin_fmaf(rz, p.z, __builtin_fmaf(ry, p.y, rx * p.x));
    const float d2 = (rq + p.w) - 2.0f * mdot;
    const unsigned key = fkey(d2);
    const unsigned t = (k1 > key) ? k1 : key;   // max(k1, key)
    k1 = (k1 < key) ? k1 : key;                 // min(k1, key)
    k2 = (k2 < t) ? k2 : t;                     // min(k2, t)
  }

  // ---- Tt = 32nd smallest of pool {k1,k2} x 64 lanes ----
  unsigned Tt = 0;
  {
    int head = 0;
    for (int it = 0; it < KNN; ++it) {
      unsigned v = (head == 0) ? k1 : ((head == 1) ? k2 : 0xFFFFFFFFu);
      unsigned m = v;
      for (int off = 1; off < 64; off <<= 1) {
        unsigned o = (unsigned)__shfl_xor((int)m, off, 64);
        m = (o < m) ? o : m;
      }
      ull win = __ballot(v == m);
      int wl = __ffsll((long long)win) - 1;
      if (lane == wl) ++head;
      Tt = m;
    }
  }

  // ---- phase B: compact candidates with key <= Tt ----
  unsigned cnt = 0;
  for (int ch = 0; ch < NPOINTS / 64; ++ch) {
    const int j = ch * 64 + lane;
    const float4 p = pos4[j];
    const float mdot = __builtin_fmaf(rz, p.z, __builtin_fmaf(ry, p.y, rx * p.x));
    const float d2 = (rq + p.w) - 2.0f * mdot;
    const unsigned key = fkey(d2);
    const bool c = (key <= Tt);
    const ull m = __ballot(c);
    if (c) {
      unsigned slot = cnt + (unsigned)__popcll(m & ((1ULL << lane) - 1ULL));
      if (slot < CAP)
        cand[wave][slot] = ((ull)key << 32) | (ull)(0xFFFFFFFFu - (unsigned)j);
    }
    cnt += (unsigned)__popcll(m);
  }
  __builtin_amdgcn_s_waitcnt(0);   // drain our ds_writes (wave-private region)

  if (cnt <= (unsigned)CAP) {
    // exact wave-parallel extraction of 32 smallest C from <=128 candidates
    ull c0 = (lane < (int)cnt) ? cand[wave][lane] : ~0ULL;
    ull c1 = ((lane + 64) < (int)cnt) ? cand[wave][lane + 64] : ~0ULL;
    ull lo = (c0 < c1) ? c0 : c1;
    ull hi = (c0 < c1) ? c1 : c0;
    int head = 0;
    for (int it = 0; it < KNN; ++it) {
      ull v = (head == 0) ? lo : ((head == 1) ? hi : ~0ULL);
      ull m = v;
      for (int off = 1; off < 64; off <<= 1) {
        ull o = shflx64(m, off);
        m = (o < m) ? o : m;
      }
      ull win = __ballot(v == m);
      int wl = __ffsll((long long)win) - 1;
      if (lane == wl) ++head;
      if (lane == 0) sel[wave][it] = m;
    }
  } else {
    // exact serial fallback (probability ~0): lane 0 insertion-select over all points
    if (lane == 0) {
      int n2 = 0;
      for (int j = 0; j < NPOINTS; ++j) {
        const float4 p = pos4[j];
        const float mdot = __builtin_fmaf(rz, p.z, __builtin_fmaf(ry, p.y, rx * p.x));
        const float d2 = (rq + p.w) - 2.0f * mdot;
        const unsigned key = fkey(d2);
        const ull C = ((ull)key << 32) | (ull)(0xFFFFFFFFu - (unsigned)j);
        if (n2 < KNN) {
          int b = n2 - 1;
          while (b >= 0 && sel[wave][b] > C) { sel[wave][b + 1] = sel[wave][b]; --b; }
          sel[wave][b + 1] = C;
          ++n2;
        } else if (C < sel[wave][KNN - 1]) {
          int b = KNN - 2;
          while (b >= 0 && sel[wave][b] > C) { sel[wave][b + 1] = sel[wave][b]; --b; }
          sel[wave][b + 1] = C;
        }
      }
    }
  }
  __builtin_amdgcn_s_waitcnt(0);

  // finalize (lane 0): decompose, sort by (key asc, idx asc), emit (as r6/r8)
  if (lane == 0) {
    unsigned kk[KNN], ii[KNN];
    for (int a = 0; a < KNN; ++a) {
      ull C = sel[wave][a];
      kk[a] = (unsigned)(C >> 32);
      ii[a] = 0xFFFFFFFFu - (unsigned)(C & 0xFFFFFFFFULL);
    }
    for (int a = 1; a < KNN; ++a) {
      unsigned ka = kk[a], ia = ii[a];
      int b = a - 1;
      while (b >= 0 && (kk[b] > ka || (kk[b] == ka && ii[b] > ia))) {
        kk[b + 1] = kk[b]; ii[b + 1] = ii[b]; --b;
      }
      kk[b + 1] = ka; ii[b + 1] = ia;
    }
    unsigned ob = (unsigned)row * KNN;
    for (int a = 0; a < KNN; ++a) idx_out[ob + a] = ii[a];
  }
}

// ===================== kernel 2: mean + cov + eigh per point (fp32) =====================
__global__ __launch_bounds__(256) void pca_kernel(const float* __restrict__ pos,
                                                  const unsigned* __restrict__ idx,
                                                  float* __restrict__ center,
                                                  float* __restrict__ Vmat) {
#pragma clang fp contract(off)
  int n = blockIdx.x * 256 + threadIdx.x;
  if (n >= NPOINTS) return;
  float sx = 0.f, sy = 0.f, sz = 0.f;
  for (int k = 0; k < KNN; ++k) {
    unsigned j = idx[n * KNN + k];
    sx += pos[j * 3 + 0];
    sy += pos[j * 3 + 1];
    sz += pos[j * 3 + 2];
  }
  float cx = sx * 0.03125f, cy = sy * 0.03125f, cz = sz * 0.03125f;
  float c00 = 0.f, c10 = 0.f, c20 = 0.f, c11 = 0.f, c21 = 0.f, c22 = 0.f;
  for (int k = 0; k < KNN; ++k) {
    unsigned j = idx[n * KNN + k];
    float lx = pos[j * 3 + 0] - cx;
    float ly = pos[j * 3 + 1] - cy;
    float lz = pos[j * 3 + 2] - cz;
    c00 += lx * lx; c10 += lx * ly; c20 += lx * lz;
    c11 += ly * ly; c21 += ly * lz; c22 += lz * lz;
  }
  c00 *= 0.03125f; c10 *= 0.03125f; c20 *= 0.03125f;
  c11 *= 0.03125f; c21 *= 0.03125f; c22 *= 0.03125f;
  float V[3][3];
  eigh3(c00, c10, c20, c11, c21, c22, V);
  center[n * 3 + 0] = cx; center[n * 3 + 1] = cy; center[n * 3 + 2] = cz;
  for (int i = 0; i < 3; ++i)
    for (int j2 = 0; j2 < 3; ++j2)
      Vmat[n * 9 + i * 3 + j2] = V[i][j2];
}

// ===================== kernel 3: basis + G[b,i] + 27x (64x64) matmuls =====================
#define NT 8
__global__ __launch_bounds__(256) void conv_kernel(const float* __restrict__ pos,
                                                   const float* __restrict__ chan,
                                                   const float* __restrict__ coeff,
                                                   const unsigned* __restrict__ idx,
                                                   const float* __restrict__ center,
                                                   const float* __restrict__ Vmat,
                                                   float* __restrict__ out) {
#pragma clang fp contract(off)
  __shared__ float G[NT][NBASIS][64];
  __shared__ float Tsh[NT][64];
  const int tid  = threadIdx.x;
  const int lane = tid & 63;
  const int wave = tid >> 6;
  const int n0 = blockIdx.x * NT;

  for (int rep = 0; rep < 2; ++rep) {
    const int nl = wave * 2 + rep;
    const int n = n0 + nl;
    const float cx = center[n * 3 + 0], cy = center[n * 3 + 1], cz = center[n * 3 + 2];
    const float V00 = Vmat[n * 9 + 0], V01 = Vmat[n * 9 + 1], V02 = Vmat[n * 9 + 2];
    const float V10 = Vmat[n * 9 + 3], V11 = Vmat[n * 9 + 4], V12 = Vmat[n * 9 + 5];
    const float V20 = Vmat[n * 9 + 6], V21 = Vmat[n * 9 + 7], V22 = Vmat[n * 9 + 8];
    float g[NBASIS];
#pragma unroll
    for (int b = 0; b < NBASIS; ++b) g[b] = 0.f;
    for (int k = 0; k < KNN; ++k) {
      const unsigned j = idx[n * KNN + k];
      const float lx = pos[j * 3 + 0] - cx;
      const float ly = pos[j * 3 + 1] - cy;
      const float lz = pos[j * 3 + 2] - cz;
      const float X  = lx * V00 + ly * V10 + lz * V20;
      const float Y  = lx * V01 + ly * V11 + lz * V21;
      const float Zc = lx * V02 + ly * V12 + lz * V22;
      const float r = sqrtf(((X * X + Y * Y) + Zc * Zc) + 1e-8f);
      float u = Zc / r;
      u = fminf(fmaxf(u, -0.999999f), 0.999999f);
      const float ct1 = u, ct2 = 2.f * u * u - 1.f;
      const float rho2 = X * X + Y * Y;
      const float cp1 = (rho2 > 0.f) ? (X / sqrtf(rho2)) : 1.f;
      const float cp2 = 2.f * cp1 * cp1 - 1.f;
      const float f = chan[(size_t)j * 64 + lane];
      const float pr1 = r, pr2 = r * r;
      float tc[9];
      tc[0] = 1.f; tc[1] = cp1; tc[2] = cp2;
      tc[3] = ct1; tc[4] = ct1 * cp1; tc[5] = ct1 * cp2;
      tc[6] = ct2; tc[7] = ct2 * cp1; tc[8] = ct2 * cp2;
#pragma unroll
      for (int m9 = 0; m9 < 9; ++m9) {
        g[m9]      = __builtin_fmaf(tc[m9],       f, g[m9]);
        g[9 + m9]  = __builtin_fmaf(pr1 * tc[m9], f, g[9 + m9]);
        g[18 + m9] = __builtin_fmaf(pr2 * tc[m9], f, g[18 + m9]);
      }
    }
#pragma unroll
    for (int b = 0; b < NBASIS; ++b) G[nl][b][lane] = g[b];
  }
  __syncthreads();

  float acc0 = 0.f, acc1 = 0.f;
  for (int b = 0; b < NBASIS; ++b) {
#pragma unroll 8
    for (int i = 0; i < 64; ++i) {
      const float c = coeff[(size_t)(b * 64 + i) * 64 + lane];
      acc0 = __builtin_fmaf(c, G[wave * 2 + 0][b][i], acc0);
      acc1 = __builtin_fmaf(c, G[wave * 2 + 1][b][i], acc1);
    }
  }
  __syncthreads();
  Tsh[wave * 2 + 0][lane] = acc0 * 0.03125f;
  Tsh[wave * 2 + 1][lane] = acc1 * 0.03125f;
  __syncthreads();
#pragma unroll
  for (int s = 0; s < 2; ++s) {
    const int el = tid + s * 256;
    const int o = el >> 3, nn = el & 7;
    out[(size_t)o * NPOINTS + (n0 + nn)] = Tsh[nn][o];
  }
}

// ===================== launch =====================
extern "C" void kernel_launch(void* const* d_in, const int* in_sizes, int n_in,
                              void* d_out, int out_size, void* d_ws, size_t ws_size,
                              hipStream_t stream) {
  (void)in_sizes; (void)n_in; (void)out_size; (void)ws_size;
  const float* pos   = (const float*)d_in[0];
  const float* chan  = (const float*)d_in[1];
  const float* coeff = (const float*)d_in[2];
  float* out = (float*)d_out;
  unsigned char* ws = (unsigned char*)d_ws;
  float4*   pos4   = (float4*)(ws);                                    // 256 KiB
  unsigned* idx    = (unsigned*)(ws + (size_t)NPOINTS * 16);           // 2 MiB
  float*    center = (float*)(ws + (size_t)NPOINTS * 16 + (size_t)NPOINTS * KNN * 4);          // 192 KiB
  float*    Vmat   = (float*)(ws + (size_t)NPOINTS * 16 + (size_t)NPOINTS * KNN * 4
                              + (size_t)NPOINTS * 12);                 // 576 KiB
  hipLaunchKernelGGL(pack_kernel, dim3(NPOINTS / 256),  dim3(256), 0, stream, pos, pos4);
  hipLaunchKernelGGL(knn_kernel,  dim3(NPOINTS / WPB),  dim3(256), 0, stream, pos4, idx);
  hipLaunchKernelGGL(pca_kernel,  dim3(NPOINTS / 256),  dim3(256), 0, stream, pos, idx, center, Vmat);
  hipLaunchKernelGGL(conv_kernel, dim3(NPOINTS / NT),   dim3(256), 0, stream, pos, chan, coeff, idx, center, Vmat, out);
}